// Round 6
// baseline (8608.297 us; speedup 1.0000x reference)
//
#include <hip/hip_runtime.h>

#define SS 4096
#define LL 16
#define HD 512
#define ECD 128
#define HHD 256

typedef __attribute__((ext_vector_type(8))) short short8;
typedef __attribute__((ext_vector_type(4))) float float4v;
typedef _Float16 half2v __attribute__((ext_vector_type(2)));

__device__ __forceinline__ float bf2f(unsigned short u){
  union { unsigned int i; float f; } v; v.i = ((unsigned int)u) << 16; return v.f;
}
__device__ __forceinline__ unsigned short f2bf(float f){
  union { float f; unsigned int i; } v; v.f = f;
  unsigned int u = v.i;
  unsigned int r = (u + 0x7fffu + ((u >> 16) & 1u)) >> 16;
  return (unsigned short)r;
}
__device__ __forceinline__ float sigf(float x){ return 1.f / (1.f + __expf(-x)); }
__device__ __forceinline__ float tanh_f(float x){
  float e = __expf(2.f * x);
  return 1.f - 2.f / (e + 1.f);
}
__device__ __forceinline__ bool badf(float x){ return !(fabsf(x) < 1e30f); }

#if __has_builtin(__builtin_amdgcn_sdot4)
__device__ __forceinline__ int SDOT4(unsigned int a, unsigned int b, int c){
  return __builtin_amdgcn_sdot4((int)a, (int)b, c, false);
}
#else
__device__ __forceinline__ int SDOT4(unsigned int a, unsigned int b, int c){
#pragma unroll
  for (int i = 0; i < 4; ++i){
    int ai = (int)(signed char)((a >> (8*i)) & 0xffu);
    int bi = (int)(signed char)((b >> (8*i)) & 0xffu);
    c += ai * bi;
  }
  return c;
}
#endif

// pack 8 f32 -> 8 bf16 (as int4) for LDS staging
__device__ __forceinline__ int4 cvt8(const float* __restrict__ s){
  union { unsigned short u[8]; int4 v; } pk;
#pragma unroll
  for (int i = 0; i < 8; ++i) pk.u[i] = f2bf(s[i]);
  return pk.v;
}

// ---------------- prep: xUb[c][n] = char_emb[c].Wih_c[n] + bih_c[n] + bhh_c[n]  (bf16 out)
__global__ void prep_xu_k(const float* __restrict__ char_emb,
                          const float* __restrict__ Wih_c,
                          const float* __restrict__ bih_c,
                          const float* __restrict__ bhh_c,
                          unsigned short* __restrict__ xUb)
{
  int idx = blockIdx.x * 256 + threadIdx.x;   // 512 * 2048
  int c = idx >> 11, n = idx & 2047;
  const float* ce = char_emb + (size_t)c * ECD;
  const float* wr = Wih_c + (size_t)n * ECD;
  float acc = bih_c[n] + bhh_c[n];
  for (int k = 0; k < ECD; k += 4) {
    float4 a = *(const float4*)(ce + k);
    float4 b = *(const float4*)(wr + k);
    acc += a.x*b.x + a.y*b.y + a.z*b.z + a.w*b.w;
  }
  xUb[idx] = f2bf(acc);
}

// ---------------- prep: h0 = prefix_emb[feat_seq] (bf16), c0 = 0 (bf16)
__global__ void prep_h0c0_k(const float* __restrict__ prefix_emb,
                            const int* __restrict__ feat_seq,
                            unsigned short* __restrict__ h0,
                            unsigned short* __restrict__ c0)
{
  int idx = blockIdx.x * 256 + threadIdx.x;  // 4096*512
  int s = idx >> 9, j = idx & 511;
  h0[idx] = f2bf(prefix_emb[(size_t)feat_seq[s] * HD + j]);
  c0[idx] = 0;
}

// ---------------- prep A: per-row scale (int8 quant), combined bias, diag init
// idx in [0, 2048): dir = idx>>10, row = idx & 1023. Whh_{dir} is [1024,256] f32.
__global__ void prep_scale_k(const float* __restrict__ Whh_f,
                             const float* __restrict__ Whh_b,
                             const float* __restrict__ bih_f,
                             const float* __restrict__ bhh_f,
                             const float* __restrict__ bih_b,
                             const float* __restrict__ bhh_b,
                             float* __restrict__ sc_comb,   // [2][1024]: s_row/127
                             float* __restrict__ inv_s,     // [2][1024]: 127/max
                             float* __restrict__ biasbuf,   // [2][1024]
                             int* __restrict__ diag)
{
  int idx = blockIdx.x * 256 + threadIdx.x;
  if (idx >= 2048) return;
  int dir = idx >> 10, row = idx & 1023;
  const float* W = (dir ? Whh_b : Whh_f) + (size_t)row * HHD;
  float m = 0.f;
  for (int k = 0; k < HHD; k += 4) {
    float4 w = *(const float4*)(W + k);
    m = fmaxf(m, fmaxf(fmaxf(fabsf(w.x), fabsf(w.y)), fmaxf(fabsf(w.z), fabsf(w.w))));
  }
  sc_comb[idx] = m / (127.f * 127.f);
  inv_s[idx]   = (m > 0.f) ? (127.f / m) : 0.f;
  biasbuf[idx] = dir ? (bih_b[row] + bhh_b[row]) : (bih_f[row] + bhh_f[row]);
  if (idx == 0) diag[0] = 0;
}

// ---------------- prep B: quantize + lane-rotate Whh into Wq[dir][g][m][t] u32
// scan thread t (lane l=t&63), vgpr index m: k=m>>2, j=m&3, chunk c=4*((k+l)&15)+j,
// word = int8x4 of W[g*256+t][4c..4c+3] quantized by row scale.
__global__ void prep_pack_k(const float* __restrict__ Whh_f,
                            const float* __restrict__ Whh_b,
                            const float* __restrict__ inv_s,
                            unsigned int* __restrict__ Wq)
{
  int idx = blockIdx.x * 256 + threadIdx.x;   // 2*4*64*256 = 131072
  int t   = idx & 255;
  int m   = (idx >> 8) & 63;
  int g   = (idx >> 14) & 3;
  int dir = (idx >> 16) & 1;
  int l = t & 63;
  int k = m >> 2, j = m & 3;
  int c = 4 * ((k + l) & 15) + j;
  int row = g * 256 + t;
  const float* W = (dir ? Whh_b : Whh_f) + (size_t)row * HHD + 4 * c;
  float inv = inv_s[dir * 1024 + row];
  unsigned int w = 0;
#pragma unroll
  for (int i = 0; i < 4; ++i) {
    int q = __float2int_rn(W[i] * inv);
    q = max(-127, min(127, q));
    w |= ((unsigned int)(q & 0xff)) << (8 * i);
  }
  Wq[((size_t)(dir * 4 + g) * 64 + m) * 256 + t] = w;
}

// ---------------- fused char-step: gates = h_in @ Whh_c^T (MFMA), then LSTM cell epilogue
__global__ __launch_bounds__(256) void gemm_char_k(
    const unsigned short* __restrict__ hin,   // [4096,512] bf16
    const float* __restrict__ Whh,            // [2048,512] f32
    const unsigned short* __restrict__ xUb,   // [512,2048] bf16
    const int* __restrict__ chars,
    const int* __restrict__ lens,
    int t,
    unsigned short* __restrict__ hout,        // [4096,512] bf16
    unsigned short* __restrict__ cb,          // [4096,512] bf16 (in/out)
    int* __restrict__ diag)
{
  __shared__ __align__(16) unsigned short As[128 * 32];
  __shared__ __align__(16) unsigned short Bs[128 * 32];
  __shared__ __align__(16) unsigned short gates[128 * 136];
  const int tid = threadIdx.x;
  const int m0 = blockIdx.y * 128;
  const int n0h = blockIdx.x * 32;            // base h-column of this tile
  const int wave = tid >> 6;
  const int lane = tid & 63;
  const int wm = (wave >> 1) * 64;
  const int wn = (wave & 1) * 64;
  float4v z = {0.f, 0.f, 0.f, 0.f};
  float4v acc[4][4];
#pragma unroll
  for (int i = 0; i < 4; ++i)
#pragma unroll
    for (int j = 0; j < 4; ++j) acc[i][j] = z;

  for (int k0 = 0; k0 < 512; k0 += 32) {
    __syncthreads();
#pragma unroll
    for (int i = 0; i < 2; ++i) {
      int chunk = tid * 2 + i;           // 0..511
      int row = chunk >> 2;              // 0..127
      int k8 = (chunk & 3) * 8;
      int4 av = *(const int4*)(hin + (size_t)(m0 + row) * 512 + k0 + k8);
      *(int4*)(As + row * 32 + k8) = av;
      int br = (row >> 5) * 512 + n0h + (row & 31);
      *(int4*)(Bs + row * 32 + k8) = cvt8(Whh + (size_t)br * 512 + k0 + k8);
    }
    __syncthreads();
    short8 af[4], bfr[4];
    const int kq = (lane >> 4) * 8;
#pragma unroll
    for (int i = 0; i < 4; ++i) {
      af[i]  = *(const short8*)(As + (wm + i * 16 + (lane & 15)) * 32 + kq);
      bfr[i] = *(const short8*)(Bs + (wn + i * 16 + (lane & 15)) * 32 + kq);
    }
#pragma unroll
    for (int i = 0; i < 4; ++i)
#pragma unroll
      for (int j = 0; j < 4; ++j)
        acc[i][j] = __builtin_amdgcn_mfma_f32_16x16x32_bf16(af[i], bfr[j], acc[i][j], 0, 0, 0);
  }
  __syncthreads();
#pragma unroll
  for (int i = 0; i < 4; ++i)
#pragma unroll
    for (int j = 0; j < 4; ++j)
#pragma unroll
      for (int r = 0; r < 4; ++r) {
        int row = wm + i * 16 + (lane >> 4) * 4 + r;
        int col = wn + j * 16 + (lane & 15);
        gates[row * 136 + col] = f2bf(acc[i][j][r]);
      }
  __syncthreads();
#pragma unroll
  for (int e = 0; e < 16; ++e) {
    int idx = e * 256 + tid;
    int r = idx >> 5, hc = idx & 31;
    int s = m0 + r;
    int col = n0h + hc;
    if (t < lens[s]) {
      int cid = chars[s * LL + t];
      size_t xb = (size_t)cid * 2048 + col;
      float gi = bf2f(gates[r * 136 + hc])      + bf2f(xUb[xb]);
      float gf = bf2f(gates[r * 136 + 32 + hc]) + bf2f(xUb[xb + 512]);
      float gg = bf2f(gates[r * 136 + 64 + hc]) + bf2f(xUb[xb + 1024]);
      float go = bf2f(gates[r * 136 + 96 + hc]) + bf2f(xUb[xb + 1536]);
      if (badf(gi + gf + gg + go)) atomicOr(diag, 1);
      float cc = sigf(gf) * bf2f(cb[(size_t)s * 512 + col]) + sigf(gi) * tanh_f(gg);
      cb[(size_t)s * 512 + col] = f2bf(cc);
      hout[(size_t)s * 512 + col] = f2bf(sigf(go) * tanh_f(cc));
    } else {
      hout[(size_t)s * 512 + col] = hin[(size_t)s * 512 + col];
    }
  }
}

// ---------------- P GEMM: P[M=4096, N=1024](bf16) = [word_emb[wseq] f32 | h bf16] @ Wih^T(f32)
__global__ __launch_bounds__(256) void gemm_gather_nt_k(
    const float* __restrict__ wemb,
    const int* __restrict__ wseq,
    const unsigned short* __restrict__ hbuf,
    const float* __restrict__ B,              // [1024,1024] f32
    unsigned short* __restrict__ P)           // [4096,1024] bf16
{
  __shared__ __align__(16) unsigned short As[128 * 32];
  __shared__ __align__(16) unsigned short Bs[128 * 32];
  const int tid = threadIdx.x;
  const int m0 = blockIdx.y * 128;
  const int n0 = blockIdx.x * 128;
  const int wave = tid >> 6;
  const int lane = tid & 63;
  const int wm = (wave >> 1) * 64;
  const int wn = (wave & 1) * 64;
  float4v z = {0.f, 0.f, 0.f, 0.f};
  float4v acc[4][4];
#pragma unroll
  for (int i = 0; i < 4; ++i)
#pragma unroll
    for (int j = 0; j < 4; ++j) acc[i][j] = z;

  for (int k0 = 0; k0 < 1024; k0 += 32) {
    __syncthreads();
#pragma unroll
    for (int i = 0; i < 2; ++i) {
      int chunk = tid * 2 + i;
      int row = chunk >> 2;
      int k8 = (chunk & 3) * 8;
      int arow = m0 + row;
      int acol = k0 + k8;
      if (acol < 512) {
        *(int4*)(As + row * 32 + k8) = cvt8(wemb + (size_t)wseq[arow] * 512 + acol);
      } else {
        int4 av = *(const int4*)(hbuf + (size_t)arow * 512 + (acol - 512));
        *(int4*)(As + row * 32 + k8) = av;
      }
      *(int4*)(Bs + row * 32 + k8) = cvt8(B + (size_t)(n0 + row) * 1024 + k0 + k8);
    }
    __syncthreads();
    short8 af[4], bfr[4];
    const int kq = (lane >> 4) * 8;
#pragma unroll
    for (int i = 0; i < 4; ++i) {
      af[i]  = *(const short8*)(As + (wm + i * 16 + (lane & 15)) * 32 + kq);
      bfr[i] = *(const short8*)(Bs + (wn + i * 16 + (lane & 15)) * 32 + kq);
    }
#pragma unroll
    for (int i = 0; i < 4; ++i)
#pragma unroll
      for (int j = 0; j < 4; ++j)
        acc[i][j] = __builtin_amdgcn_mfma_f32_16x16x32_bf16(af[i], bfr[j], acc[i][j], 0, 0, 0);
  }
#pragma unroll
  for (int i = 0; i < 4; ++i)
#pragma unroll
    for (int j = 0; j < 4; ++j)
#pragma unroll
      for (int r = 0; r < 4; ++r) {
        int row = m0 + wm + i * 16 + (lane >> 4) * 4 + r;
        int col = n0 + wn + j * 16 + (lane & 15);
        P[(size_t)row * 1024 + col] = f2bf(acc[i][j][r]);
      }
}

// ---------------- single-WG-per-direction recurrent scan, int8 weights in VGPRs.
// 256 threads (4 waves, 1/SIMD, <=512 VGPR). Thread t owns col t: all 4 gate rows
// (g*256+t), the cell state c (register), h output. h broadcast via LDS int8
// (hq[2][64] u32), weights lane-rotated so hq reads are conflict-free.
// ONE barrier per step: iter ts reads hq[ts&1] (pre-barrier writes of prev iter),
// writes hq[(ts+1)&1]; overwrite of slot ts&1 only happens in iter ts+1, i.e.
// after the barrier that ends iter ts, by which time all reads of it completed.
__global__ __launch_bounds__(256, 1) void scan2_k(
    const unsigned short* __restrict__ P_f,   // [4096,1024] bf16
    const unsigned short* __restrict__ P_b,
    const unsigned int* __restrict__ Wq,      // [2][4][64][256] u32 (rotated int8x4)
    const float* __restrict__ sc_comb,        // [2][1024]
    const float* __restrict__ biasbuf,        // [2][1024]
    unsigned short* __restrict__ out_f,       // [4096,256] bf16
    unsigned short* __restrict__ out_b,
    int dirFixed)
{
  const int dir = (dirFixed < 0) ? (int)blockIdx.x : dirFixed;
  const int t = threadIdx.x;
  const int l = t & 63;
  __shared__ __align__(16) unsigned int hq[2][64];

  // ---- register-resident rotated weights: 256 u32 ----
  unsigned int w0[64], w1[64], w2[64], w3[64];
  {
    const unsigned int* Wd = Wq + (size_t)dir * 4 * 64 * 256;
#pragma unroll
    for (int m = 0; m < 64; ++m) {
      w0[m] = Wd[(size_t)(0 * 64 + m) * 256 + t];
      w1[m] = Wd[(size_t)(1 * 64 + m) * 256 + t];
      w2[m] = Wd[(size_t)(2 * 64 + m) * 256 + t];
      w3[m] = Wd[(size_t)(3 * 64 + m) * 256 + t];
    }
  }
  const float sc0 = sc_comb[dir * 1024 + t];
  const float sc1 = sc_comb[dir * 1024 + 256 + t];
  const float sc2 = sc_comb[dir * 1024 + 512 + t];
  const float sc3 = sc_comb[dir * 1024 + 768 + t];
  const float b0 = biasbuf[dir * 1024 + t];
  const float b1 = biasbuf[dir * 1024 + 256 + t];
  const float b2 = biasbuf[dir * 1024 + 512 + t];
  const float b3 = biasbuf[dir * 1024 + 768 + t];
  const unsigned short* P = dir ? P_b : P_f;
  unsigned short* out = dir ? out_b : out_f;

  if (t < 64) hq[0][t] = 0u;

  // prefetch P row for step 0
  int srow = dir ? 4095 : 0;
  float pc0 = bf2f(P[(size_t)srow * 1024 + t]);
  float pc1 = bf2f(P[(size_t)srow * 1024 + 256 + t]);
  float pc2 = bf2f(P[(size_t)srow * 1024 + 512 + t]);
  float pc3 = bf2f(P[(size_t)srow * 1024 + 768 + t]);
  float c = 0.f;
  __syncthreads();

  for (int ts = 0; ts < 4096; ++ts) {
    const int slot = ts & 1;
    // issue next P row loads early; whole dot hides their latency
    float pn0 = pc0, pn1 = pc1, pn2 = pc2, pn3 = pc3;
    if (ts < 4095) {
      const int srow2 = dir ? (4094 - ts) : (ts + 1);
      pn0 = bf2f(P[(size_t)srow2 * 1024 + t]);
      pn1 = bf2f(P[(size_t)srow2 * 1024 + 256 + t]);
      pn2 = bf2f(P[(size_t)srow2 * 1024 + 512 + t]);
      pn3 = bf2f(P[(size_t)srow2 * 1024 + 768 + t]);
    }
    // dot: 8 ILP chains (2 per gate)
    int a0 = 0, a1 = 0, a2 = 0, a3 = 0, a4 = 0, a5 = 0, a6 = 0, a7 = 0;
#pragma unroll
    for (int k = 0; k < 16; ++k) {
      const int q = (k + l) & 15;
      uint4 hv = *(const uint4*)&hq[slot][4 * q];
      a0 = SDOT4(w0[4 * k + 0], hv.x, a0); a4 = SDOT4(w0[4 * k + 1], hv.y, a4);
      a0 = SDOT4(w0[4 * k + 2], hv.z, a0); a4 = SDOT4(w0[4 * k + 3], hv.w, a4);
      a1 = SDOT4(w1[4 * k + 0], hv.x, a1); a5 = SDOT4(w1[4 * k + 1], hv.y, a5);
      a1 = SDOT4(w1[4 * k + 2], hv.z, a1); a5 = SDOT4(w1[4 * k + 3], hv.w, a5);
      a2 = SDOT4(w2[4 * k + 0], hv.x, a2); a6 = SDOT4(w2[4 * k + 1], hv.y, a6);
      a2 = SDOT4(w2[4 * k + 2], hv.z, a2); a6 = SDOT4(w2[4 * k + 3], hv.w, a6);
      a3 = SDOT4(w3[4 * k + 0], hv.x, a3); a7 = SDOT4(w3[4 * k + 1], hv.y, a7);
      a3 = SDOT4(w3[4 * k + 2], hv.z, a3); a7 = SDOT4(w3[4 * k + 3], hv.w, a7);
    }
    const float gi = (float)(a0 + a4) * sc0 + b0 + pc0;
    const float gf = (float)(a1 + a5) * sc1 + b1 + pc1;
    const float gg = (float)(a2 + a6) * sc2 + b2 + pc2;
    const float go = (float)(a3 + a7) * sc3 + b3 + pc3;
    const float cc = sigf(gf) * c + sigf(gi) * tanh_f(gg);
    c = cc;
    const float hh = sigf(go) * tanh_f(cc);
    out[(size_t)srow * HHD + t] = f2bf(hh);
    if (ts < 4095) {
      int qh = __float2int_rn(hh * 127.f);
      qh = max(-127, min(127, qh));
      ((char*)&hq[slot ^ 1][0])[t] = (char)qh;
    }
    pc0 = pn0; pc1 = pn1; pc2 = pn2; pc3 = pn3;
    srow += dir ? -1 : 1;
    __syncthreads();
  }
}

// ---------------- heads: logits + log_softmax -> f32 out
__global__ __launch_bounds__(128) void head_k(
    const unsigned short* __restrict__ out_f, const unsigned short* __restrict__ out_b,
    const float* __restrict__ Wpos, const float* __restrict__ bpos,
    const float* __restrict__ Wner, const float* __restrict__ bner,
    float* __restrict__ dout, int* __restrict__ diag)
{
  const int s = blockIdx.x, tid = threadIdx.x;
  __shared__ __align__(16) float xv[512];
#pragma unroll
  for (int i = 0; i < 4; ++i) {
    int k = tid * 4 + i;
    xv[k] = (k < 256) ? bf2f(out_f[(size_t)s * 256 + k])
                      : bf2f(out_b[(size_t)s * 256 + (k - 256)]);
  }
  __syncthreads();
  float logit = 0.f;
  const int j = tid;
  if (j < 96) {
    const float* wr = (j < 64) ? (Wpos + (size_t)j * 512)
                               : (Wner + (size_t)(j - 64) * 512);
    float b = (j < 64) ? bpos[j] : bner[j - 64];
    float acc = 0.f;
    for (int k = 0; k < 512; k += 4) {
      float4 wv = *(const float4*)(wr + k);
      acc += xv[k] * wv.x + xv[k + 1] * wv.y + xv[k + 2] * wv.z + xv[k + 3] * wv.w;
    }
    logit = acc + b;
    if (badf(logit)) { atomicOr(diag, 4); logit = 0.f; }
  }
  if (j < 64) {
    float m = logit;
    for (int o = 32; o >= 1; o >>= 1) m = fmaxf(m, __shfl_xor(m, o));
    float e = __expf(logit - m), sum = e;
    for (int o = 32; o >= 1; o >>= 1) sum += __shfl_xor(sum, o);
    float v = logit - m - logf(sum);
    if (!(v > -1e30f && v < 1e30f)) v = -111.f;
    dout[(size_t)s * 64 + j] = v;
  } else if (j < 96) {
    float m = logit;
    for (int o = 16; o >= 1; o >>= 1) m = fmaxf(m, __shfl_xor(m, o, 32));
    float e = __expf(logit - m), sum = e;
    for (int o = 16; o >= 1; o >>= 1) sum += __shfl_xor(sum, o, 32);
    float v = logit - m - logf(sum);
    if (!(v > -1e30f && v < 1e30f)) v = -111.f;
    dout[262144 + (size_t)s * 32 + (j - 64)] = v;
  }
}

// ---------------- diagnostics (silent when healthy)
__global__ void diag_k(const float* __restrict__ ce,
                       int* __restrict__ diag,
                       float* __restrict__ dout)
{
  int cnt = 0;
  for (int i = 0; i < 64; ++i) {
    float x = ce[i];
    if (x == x && fabsf(x) < 100.f) cnt++;
  }
  if (cnt < 48) diag[0] |= 8;
  int d = diag[0];
  if (d) dout[0] = 1000.f + 100.f * (float)d;
}

__global__ void wssmall_k(float* __restrict__ dout, int mb)
{
  dout[0] = 10000.f + (float)mb;
}

extern "C" void kernel_launch(void* const* d_in, const int* in_sizes, int n_in,
                              void* d_out, int out_size, void* d_ws, size_t ws_size,
                              hipStream_t stream) {
  const int*   word_seq  = (const int*)d_in[0];
  const int*   chars     = (const int*)d_in[1];
  const int*   char_lens = (const int*)d_in[2];
  const int*   feat_seq  = (const int*)d_in[3];
  const float* char_emb  = (const float*)d_in[4];
  const float* word_emb  = (const float*)d_in[5];
  const float* prefix_emb= (const float*)d_in[6];
  const float* Wih_c     = (const float*)d_in[7];
  const float* Whh_c     = (const float*)d_in[8];
  const float* bih_c     = (const float*)d_in[9];
  const float* bhh_c     = (const float*)d_in[10];
  const float* Wih_f     = (const float*)d_in[11];
  const float* Whh_f     = (const float*)d_in[12];
  const float* bih_f     = (const float*)d_in[13];
  const float* bhh_f     = (const float*)d_in[14];
  const float* Wih_b     = (const float*)d_in[15];
  const float* Whh_b     = (const float*)d_in[16];
  const float* bih_b     = (const float*)d_in[17];
  const float* bhh_b     = (const float*)d_in[18];
  const float* Wpos      = (const float*)d_in[19];
  const float* bpos      = (const float*)d_in[20];
  const float* Wner      = (const float*)d_in[21];
  const float* bner      = (const float*)d_in[22];
  float* dout = (float*)d_out;

  const size_t MB = 1048576;
  char* ws = (char*)d_ws;
  // small region
  int*            diag  = (int*)(ws + 512);            // 512 B
  float*          bias2 = (float*)(ws + 8192);         // 8 KB [2][1024]
  float*          scomb = (float*)(ws + 16384);        // 8 KB [2][1024]
  float*          sinv  = (float*)(ws + 24576);        // 8 KB [2][1024]
  unsigned int*   Wq    = (unsigned int*)(ws + 65536); // 512 KB [2][4][64][256]
  // big region (phase-overlapped)
  unsigned short* hA    = (unsigned short*)(ws + 2 * MB);   // 4 MB [4096,512] bf16
  unsigned short* hB    = (unsigned short*)(ws + 6 * MB);   // 4 MB
  unsigned short* xUb   = (unsigned short*)(ws + 10 * MB);  // 2 MB [512,2048] bf16
  unsigned short* cb    = (unsigned short*)(ws + 12 * MB);  // 4 MB [4096,512] bf16

  const size_t NEED_A2 = 22 * MB;  // P_f 6..14, P_b 14..22 (both scans in parallel)
  const size_t NEED_B  = 16 * MB;  // sequential dir scans, shared P buffer
  unsigned short* P_f;
  unsigned short* P_b;
  unsigned short* out_f;
  unsigned short* out_b;
  int layoutA;
  if (ws_size >= NEED_A2) {
    layoutA = 1;
    P_f   = (unsigned short*)(ws + 6 * MB);    // over dead hB/xUb
    P_b   = (unsigned short*)(ws + 14 * MB);   // over dead cb + fresh
    out_f = (unsigned short*)(ws + 2 * MB);    // over dead hA
    out_b = (unsigned short*)(ws + 4 * MB);
  } else if (ws_size >= NEED_B) {
    layoutA = 0;
    P_f   = (unsigned short*)(ws + 6 * MB);
    P_b   = (unsigned short*)(ws + 6 * MB);
    out_f = (unsigned short*)(ws + 14 * MB);
    out_b = (unsigned short*)(ws + 2 * MB);
  } else {
    wssmall_k<<<1, 1, 0, stream>>>(dout, (int)(ws_size >> 20));
    return;
  }

  prep_xu_k<<<(512 * 2048) / 256, 256, 0, stream>>>(char_emb, Wih_c, bih_c, bhh_c, xUb);
  prep_h0c0_k<<<(4096 * 512) / 256, 256, 0, stream>>>(prefix_emb, feat_seq, hA, cb);
  prep_scale_k<<<8, 256, 0, stream>>>(Whh_f, Whh_b, bih_f, bhh_f, bih_b, bhh_b,
                                      scomb, sinv, bias2, diag);
  prep_pack_k<<<512, 256, 0, stream>>>(Whh_f, Whh_b, sinv, Wq);

  unsigned short* hcur = hA;
  unsigned short* hnxt = hB;
  for (int t = 0; t < 16; ++t) {
    gemm_char_k<<<dim3(16, 32), 256, 0, stream>>>(
        hcur, Whh_c, xUb, chars, char_lens, t, hnxt, cb, diag);
    unsigned short* tmp = hcur; hcur = hnxt; hnxt = tmp;
  }
  // after 16 swaps, final char features are in hA (hcur == hA)

  if (layoutA) {
    gemm_gather_nt_k<<<dim3(8, 32), 256, 0, stream>>>(word_emb, word_seq, hcur, Wih_f, P_f);
    gemm_gather_nt_k<<<dim3(8, 32), 256, 0, stream>>>(word_emb, word_seq, hcur, Wih_b, P_b);
    scan2_k<<<2, 256, 0, stream>>>(P_f, P_b, Wq, scomb, bias2, out_f, out_b, -1);
  } else {
    gemm_gather_nt_k<<<dim3(8, 32), 256, 0, stream>>>(word_emb, word_seq, hcur, Wih_f, P_f);
    scan2_k<<<1, 256, 0, stream>>>(P_f, P_b, Wq, scomb, bias2, out_f, out_b, 0);
    gemm_gather_nt_k<<<dim3(8, 32), 256, 0, stream>>>(word_emb, word_seq, hcur, Wih_b, P_b);
    scan2_k<<<1, 256, 0, stream>>>(P_f, P_b, Wq, scomb, bias2, out_f, out_b, 1);
  }

  head_k<<<4096, 128, 0, stream>>>(out_f, out_b, Wpos, bpos, Wner, bner, dout, diag);

  diag_k<<<1, 1, 0, stream>>>(char_emb, diag, dout);
}